// Round 5
// baseline (451.264 us; speedup 1.0000x reference)
//
#include <hip/hip_runtime.h>
#include <math.h>

#define TOKENS 8192
#define DIM 4096
#define NEXP 256
#define TK 8
#define ROUTE_SCALE 2.5f
#define EMARG 1e-5f   // logit-equivalent error bound w/ safety; margins = (d_i+d_j)*EMARG

#define BM 64
#define BN 64
#define BK 64
#define PITCH 72   // halfs per LDS row

typedef _Float16 half8 __attribute__((ext_vector_type(8)));
typedef _Float16 half4v __attribute__((ext_vector_type(4)));
typedef float f4 __attribute__((ext_vector_type(4)));

union H8 { half8 v; int4 q; };

// ---------------------------------------------------------------------------
// Pre-kernel: W -> (W*256) f16 hi + residual*2048 f16 lo. Also zeroes flag_cnt.
// ---------------------------------------------------------------------------
__global__ __launch_bounds__(256) void wsplit(const float* __restrict__ W,
                                              _Float16* __restrict__ Wh,
                                              _Float16* __restrict__ Wl,
                                              int* __restrict__ flag_cnt) {
    if (blockIdx.x == 0 && threadIdx.x == 0) *flag_cnt = 0;
    int i = blockIdx.x * 256 + threadIdx.x;
    float4 w = ((const float4*)W)[i];
    const float* wf = (const float*)&w;
    half4v h, l;
#pragma unroll
    for (int j = 0; j < 4; j++) {
        float ws = wf[j] * 256.0f;
        _Float16 hj = (_Float16)ws;
        float r = ws - (float)hj;
        h[j] = hj;
        l[j] = (_Float16)(r * 2048.0f);
    }
    *(half4v*)(Wh + 4 * (size_t)i) = h;
    *(half4v*)(Wl + 4 * (size_t)i) = l;
}

// ---------------------------------------------------------------------------
// Kernel 1: scores = sigmoid(x@W^T), 3-term f16-split MFMA.
// BM=BN=BK=64, 256 thr (4 waves, 2x2 wave grid, wave tile 32x32).
// Double-buffered LDS, ONE barrier per ktile, depth-2 A register prefetch.
// Grid 512 blocks = 2 blocks/CU = 8 waves/CU.
// ---------------------------------------------------------------------------
__global__ __launch_bounds__(256) void score_gemm(const float* __restrict__ x,
                                                  const _Float16* __restrict__ Wh,
                                                  const _Float16* __restrict__ Wl,
                                                  float* __restrict__ scores) {
    __shared__ __align__(16) _Float16 sAh[2][BM * PITCH];
    __shared__ __align__(16) _Float16 sAl[2][BM * PITCH];

    const int m0 = blockIdx.x * BM;
    const int e0 = blockIdx.y * BN;
    const int tid = threadIdx.x;
    const int lane = tid & 63;
    const int wave = tid >> 6;
    const int wm = (wave >> 1) * 32;
    const int wn = (wave & 1) * 32;

    // A staging: thread owns row ar, 16 consecutive cols ac..ac+15 of 64x64 tile
    const int ar = tid >> 2;
    const int ac = (tid & 3) * 16;
    const float* xa = x + (size_t)(m0 + ar) * DIM + ac;

    const int b_row = e0 + wn + (lane & 15);
    const int b_k = (lane >> 4) * 8;

    f4 accH[2][2], accC[2][2];
#pragma unroll
    for (int i = 0; i < 2; i++)
#pragma unroll
        for (int j = 0; j < 2; j++) { accH[i][j] = (f4)0.0f; accC[i][j] = (f4)0.0f; }

    float4 areg0[4], areg1[4];

#define LOADA(DST, KT)                                                         \
    _Pragma("unroll") for (int i_ = 0; i_ < 4; i_++)                           \
        DST[i_] = *(const float4*)(xa + (size_t)(KT) * BK + 4 * i_);

#define CONVA(SRC, B)                                                          \
    {                                                                          \
        const float* f_ = (const float*)SRC;                                   \
        _Pragma("unroll") for (int h_ = 0; h_ < 2; h_++) {                     \
            H8 hh_, hl_;                                                       \
            _Pragma("unroll") for (int j_ = 0; j_ < 8; j_++) {                 \
                float xv_ = f_[8 * h_ + j_] * 16.0f;                           \
                _Float16 hv_ = (_Float16)xv_;                                  \
                float r_ = xv_ - (float)hv_;                                   \
                hh_.v[j_] = hv_;                                               \
                hl_.v[j_] = (_Float16)(r_ * 2048.0f);                          \
            }                                                                  \
            *(int4*)&sAh[B][ar * PITCH + ac + 8 * h_] = hh_.q;                 \
            *(int4*)&sAl[B][ar * PITCH + ac + 8 * h_] = hl_.q;                 \
        }                                                                      \
    }

#define KSTEP(KT, CUR, NXT, AREGC, AREGN)                                      \
    {                                                                          \
        half8 bh_[2][2], bl_[2][2];                                            \
        _Pragma("unroll") for (int s_ = 0; s_ < 2; s_++)                       \
            _Pragma("unroll") for (int nt_ = 0; nt_ < 2; nt_++) {              \
                size_t off_ = (size_t)(b_row + nt_ * 16) * DIM                 \
                              + (size_t)(KT) * BK + s_ * 32 + b_k;             \
                bh_[s_][nt_] = *(const half8*)(Wh + off_);                     \
                bl_[s_][nt_] = *(const half8*)(Wl + off_);                     \
            }                                                                  \
        if ((KT) + 2 < DIM / BK) { LOADA(AREGC, (KT) + 2) }                    \
        _Pragma("unroll") for (int s_ = 0; s_ < 2; s_++) {                     \
            half8 ah_[2], al_[2];                                              \
            _Pragma("unroll") for (int mt_ = 0; mt_ < 2; mt_++) {              \
                int rr_ = wm + mt_ * 16 + (lane & 15);                         \
                int cc_ = s_ * 32 + b_k;                                       \
                ah_[mt_] = *(const half8*)&sAh[CUR][rr_ * PITCH + cc_];        \
                al_[mt_] = *(const half8*)&sAl[CUR][rr_ * PITCH + cc_];        \
            }                                                                  \
            _Pragma("unroll") for (int mt_ = 0; mt_ < 2; mt_++)                \
                _Pragma("unroll") for (int nt_ = 0; nt_ < 2; nt_++) {          \
                    accH[mt_][nt_] = __builtin_amdgcn_mfma_f32_16x16x32_f16(   \
                        ah_[mt_], bh_[s_][nt_], accH[mt_][nt_], 0, 0, 0);      \
                    accC[mt_][nt_] = __builtin_amdgcn_mfma_f32_16x16x32_f16(   \
                        ah_[mt_], bl_[s_][nt_], accC[mt_][nt_], 0, 0, 0);      \
                    accC[mt_][nt_] = __builtin_amdgcn_mfma_f32_16x16x32_f16(   \
                        al_[mt_], bh_[s_][nt_], accC[mt_][nt_], 0, 0, 0);      \
                }                                                              \
        }                                                                      \
        if ((KT) + 1 < DIM / BK) { CONVA(AREGN, NXT) }                         \
        __syncthreads();                                                       \
    }

    // prologue: A0 -> buf0, A1 staged in regs
    LOADA(areg0, 0)
    CONVA(areg0, 0)
    LOADA(areg1, 1)
    __syncthreads();

    for (int kt2 = 0; kt2 < DIM / BK / 2; ++kt2) {
        const int kt = 2 * kt2;
        KSTEP(kt, 0, 1, areg0, areg1)       // compute buf0; convert A(kt+1)->buf1; prefetch A(kt+2)->areg0
        KSTEP(kt + 1, 1, 0, areg1, areg0)   // compute buf1; convert A(kt+2)->buf0; prefetch A(kt+3)->areg1
    }

    // epilogue: recombine, sigmoid, store. C layout: col=lane&15, row=quad*4+r
#pragma unroll
    for (int mt = 0; mt < 2; mt++)
#pragma unroll
        for (int nt = 0; nt < 2; nt++) {
            int m = m0 + wm + mt * 16 + ((lane >> 4) << 2);
            int e = e0 + wn + nt * 16 + (lane & 15);
#pragma unroll
            for (int r = 0; r < 4; r++) {
                float v = (accH[mt][nt][r] + accC[mt][nt][r] * (1.0f / 2048.0f)) * (1.0f / 4096.0f);
                scores[(size_t)(m + r) * NEXP + e] = 1.0f / (1.0f + expf(-v));
            }
        }
}

// ---------------------------------------------------------------------------
// Kernel 2: routing + derivative-weighted margin flagging.
// Score error model: |s_computed - s_exact| <= s(1-s)*EMARG. A comparison
// a vs b is trusted iff gap > (d_a+d_b)*EMARG; otherwise token is flagged.
// ---------------------------------------------------------------------------
__global__ __launch_bounds__(256) void route_kernel(const float* __restrict__ scores,
                                                    const float* __restrict__ bias,
                                                    float* __restrict__ out_w,
                                                    float* __restrict__ out_i,
                                                    int* __restrict__ flag_cnt,
                                                    int* __restrict__ flag_list) {
    const int t = blockIdx.x * 4 + (threadIdx.x >> 6);
    const int l = threadIdx.x & 63;

    float4 sc4 = *(const float4*)&scores[(size_t)t * NEXP + (l << 2)];
    float4 b4 = *(const float4*)&bias[l << 2];
    float sc[4] = {sc4.x, sc4.y, sc4.z, sc4.w};
    float sb[4] = {sc4.x + b4.x, sc4.y + b4.y, sc4.z + b4.z, sc4.w + b4.w};
    float d[4];
#pragma unroll
    for (int c = 0; c < 4; c++) d[c] = sc[c] * (1.0f - sc[c]);   // sigmoid derivative

    // per-lane top-3 (value, deriv) of its 4 biased scores
    float v1 = sb[0], v2 = -1e30f, v3 = -1e30f;
    float dd1 = d[0], dd2 = 0.0f, dd3 = 0.0f;
#pragma unroll
    for (int c = 1; c < 4; c++) {
        float xv = sb[c], xd = d[c];
        if (xv > v1) { v3 = v2; dd3 = dd2; v2 = v1; dd2 = dd1; v1 = xv; dd1 = xd; }
        else if (xv > v2) { v3 = v2; dd3 = dd2; v2 = xv; dd2 = xd; }
        else if (xv > v3) { v3 = xv; dd3 = xd; }
    }

    // butterfly merge of top-3 lists across the 8 lanes of the group
#pragma unroll
    for (int m = 1; m < 8; m <<= 1) {
        float o1 = __shfl_xor(v1, m, 64), od1 = __shfl_xor(dd1, m, 64);
        float o2 = __shfl_xor(v2, m, 64), od2 = __shfl_xor(dd2, m, 64);
        float o3 = __shfl_xor(v3, m, 64), od3 = __shfl_xor(dd3, m, 64);
        bool aw = (v1 >= o1);
        float A1 = aw ? v1 : o1, Ad1 = aw ? dd1 : od1;
        float A2 = aw ? v2 : o2, Ad2 = aw ? dd2 : od2;
        float A3 = aw ? v3 : o3, Ad3 = aw ? dd3 : od3;
        float B1 = aw ? o1 : v1, Bd1 = aw ? od1 : dd1;
        float B2 = aw ? o2 : v2, Bd2 = aw ? od2 : dd2;
        float n2, nd2, n3, nd3;
        if (A2 >= B1) { n2 = A2; nd2 = Ad2; bool c3 = (B1 >= A3); n3 = c3 ? B1 : A3; nd3 = c3 ? Bd1 : Ad3; }
        else          { n2 = B1; nd2 = Bd1; bool c3 = (A2 >= B2); n3 = c3 ? A2 : B2; nd3 = c3 ? Ad2 : Bd2; }
        v1 = A1; dd1 = Ad1; v2 = n2; dd2 = nd2; v3 = n3; dd3 = nd3;
    }
    float gscore = v1 + v2;
    float gdsum = dd1 + dd2;
    float met23 = (v2 - v3) - (dd2 + dd3) * EMARG;   // within-group top2-vs-3 trust
#pragma unroll
    for (int m = 8; m < 64; m <<= 1) met23 = fminf(met23, __shfl_xor(met23, m, 64));

    float gs[8], gd[8];
#pragma unroll
    for (int g = 0; g < 8; g++) { gs[g] = __shfl(gscore, g << 3, 64); gd[g] = __shfl(gdsum, g << 3, 64); }

    const int mygrp = l >> 3;
    int rank = 0;
#pragma unroll
    for (int g = 0; g < 8; g++) {
        bool better = (gs[g] > gscore) || (gs[g] == gscore && g < mygrp);
        rank += (g != mygrp && better) ? 1 : 0;
    }
    const bool sel = rank < 4;

    float dmaxg = 0.0f;
#pragma unroll
    for (int g = 0; g < 8; g++) dmaxg = fmaxf(dmaxg, gd[g]);
    float minsel = 1e30f, maxuns = -1e30f;
#pragma unroll
    for (int g = 0; g < 8; g++) {
        int rg = 0;
#pragma unroll
        for (int g2 = 0; g2 < 8; g2++)
            rg += (g2 != g && ((gs[g2] > gs[g]) || (gs[g2] == gs[g] && g2 < g))) ? 1 : 0;
        if (rg < 4) minsel = fminf(minsel, gs[g]); else maxuns = fmaxf(maxuns, gs[g]);
    }
    float met45 = (minsel - maxuns) - 2.0f * dmaxg * EMARG;   // group 4th-vs-5th trust

    float cand[4], cd[4];
#pragma unroll
    for (int c = 0; c < 4; c++) { cand[c] = sel ? sb[c] : 0.0f; cd[c] = sel ? d[c] : 0.0f; }

    // serial top-9 extraction with derivative carry (9th only for boundary gap)
    float wv[8], wi[8], vb[9], db[9];
    float wsum = 0.0f;
#pragma unroll
    for (int r = 0; r < 9; r++) {
        float v = cand[0];
        int idx = (l << 2);
#pragma unroll
        for (int c = 1; c < 4; c++) {
            if (cand[c] > v) { v = cand[c]; idx = (l << 2) + c; }
        }
#pragma unroll
        for (int m = 32; m >= 1; m >>= 1) {
            float ov = __shfl_xor(v, m, 64);
            int oi = __shfl_xor(idx, m, 64);
            if (ov > v || (ov == v && oi < idx)) { v = ov; idx = oi; }
        }
        vb[r] = v;
        const int cc = idx & 3;       // wave-uniform
        const int owner = idx >> 2;
        float dsel = (cc == 0) ? cd[0] : (cc == 1) ? cd[1] : (cc == 2) ? cd[2] : cd[3];
        db[r] = __shfl(dsel, owner, 64);
        if (r < 8) {
            const bool own = (owner == l);
            cand[0] = (own && cc == 0) ? -__builtin_inff() : cand[0];
            cand[1] = (own && cc == 1) ? -__builtin_inff() : cand[1];
            cand[2] = (own && cc == 2) ? -__builtin_inff() : cand[2];
            cand[3] = (own && cc == 3) ? -__builtin_inff() : cand[3];
            float tmp = (cc == 0) ? sc[0] : (cc == 1) ? sc[1] : (cc == 2) ? sc[2] : sc[3];
            float ws = __shfl(tmp, owner, 64);
            wv[r] = ws;
            wi[r] = (float)idx;
            wsum += ws;
        }
    }
    float met8 = 1e30f;
#pragma unroll
    for (int r = 0; r < 8; r++) met8 = fminf(met8, (vb[r] - vb[r + 1]) - (db[r] + db[r + 1]) * EMARG);

    const float scale = ROUTE_SCALE / wsum;
    if (l == 0) {
        float* ow = out_w + (size_t)t * TK;
        float* oi = out_i + (size_t)t * TK;
#pragma unroll
        for (int r = 0; r < 8; r++) ow[r] = wv[r] * scale;
#pragma unroll
        for (int r = 0; r < 8; r++) oi[r] = wi[r];
        if (met23 < 0.0f || met45 < 0.0f || met8 < 0.0f) {
            int pos = atomicAdd(flag_cnt, 1);
            flag_list[pos] = t;
        }
    }
}

// ---------------------------------------------------------------------------
// Kernel 3: fixup — flagged tokens get the bit-identical serial fp32 fmaf
// chain (== round-1 passing kernel) + exact re-route.
// ---------------------------------------------------------------------------
__global__ __launch_bounds__(256) void fixup_kernel(const float* __restrict__ x,
                                                    const float* __restrict__ W,
                                                    const float* __restrict__ bias,
                                                    const int* __restrict__ flag_cnt,
                                                    const int* __restrict__ flag_list,
                                                    float* __restrict__ out_w,
                                                    float* __restrict__ out_i) {
    __shared__ float S[NEXP];
    const int n = *flag_cnt;
    for (int i = blockIdx.x; i < n; i += gridDim.x) {
        const int t = flag_list[i];
        const float* xr = x + (size_t)t * DIM;
        const float* wr = W + (size_t)threadIdx.x * DIM;
        float acc = 0.0f;
        for (int k = 0; k < DIM; k += 4) {           // strictly k-serial fmaf chain
            float4 xv = *(const float4*)(xr + k);
            float4 wv = *(const float4*)(wr + k);
            acc = fmaf(xv.x, wv.x, acc);
            acc = fmaf(xv.y, wv.y, acc);
            acc = fmaf(xv.z, wv.z, acc);
            acc = fmaf(xv.w, wv.w, acc);
        }
        S[threadIdx.x] = 1.0f / (1.0f + expf(-acc));
        __syncthreads();
        if (threadIdx.x < 64) {
            const int l = threadIdx.x;
            float sc[4] = {S[4 * l], S[4 * l + 1], S[4 * l + 2], S[4 * l + 3]};
            float4 b4 = *(const float4*)&bias[4 * l];
            float sb[4] = {sc[0] + b4.x, sc[1] + b4.y, sc[2] + b4.z, sc[3] + b4.w};

            float h1 = fmaxf(sb[0], sb[1]), q1 = fminf(sb[0], sb[1]);
            float h2 = fmaxf(sb[2], sb[3]), q2 = fminf(sb[2], sb[3]);
            float m1 = fmaxf(h1, h2);
            float m2 = fmaxf(fminf(h1, h2), fmaxf(q1, q2));
#pragma unroll
            for (int m = 1; m < 8; m <<= 1) {
                float o1 = __shfl_xor(m1, m, 64);
                float o2 = __shfl_xor(m2, m, 64);
                float nm1 = fmaxf(m1, o1);
                float nm2 = fmaxf(fminf(m1, o1), fmaxf(m2, o2));
                m1 = nm1; m2 = nm2;
            }
            float gscore = m1 + m2;
            float gs[8];
#pragma unroll
            for (int g = 0; g < 8; g++) gs[g] = __shfl(gscore, g << 3, 64);
            const int mygrp = l >> 3;
            int rank = 0;
#pragma unroll
            for (int g = 0; g < 8; g++) {
                bool better = (gs[g] > gscore) || (gs[g] == gscore && g < mygrp);
                rank += (g != mygrp && better) ? 1 : 0;
            }
            const bool selg = rank < 4;
            float cand[4];
#pragma unroll
            for (int c = 0; c < 4; c++) cand[c] = selg ? sb[c] : 0.0f;
            float wv[8], wi[8];
            float wsum = 0.0f;
#pragma unroll
            for (int r = 0; r < 8; r++) {
                float v = cand[0];
                int idx = (l << 2);
#pragma unroll
                for (int c = 1; c < 4; c++) {
                    if (cand[c] > v) { v = cand[c]; idx = (l << 2) + c; }
                }
#pragma unroll
                for (int m = 32; m >= 1; m >>= 1) {
                    float ov = __shfl_xor(v, m, 64);
                    int oi = __shfl_xor(idx, m, 64);
                    if (ov > v || (ov == v && oi < idx)) { v = ov; idx = oi; }
                }
                const int cc = idx & 3;
                const bool own = (idx >> 2) == l;
                cand[0] = (own && cc == 0) ? -__builtin_inff() : cand[0];
                cand[1] = (own && cc == 1) ? -__builtin_inff() : cand[1];
                cand[2] = (own && cc == 2) ? -__builtin_inff() : cand[2];
                cand[3] = (own && cc == 3) ? -__builtin_inff() : cand[3];
                float tmp = (cc == 0) ? sc[0] : (cc == 1) ? sc[1] : (cc == 2) ? sc[2] : sc[3];
                float ws = __shfl(tmp, idx >> 2, 64);
                wv[r] = ws;
                wi[r] = (float)idx;
                wsum += ws;
            }
            const float scale = ROUTE_SCALE / wsum;
            if (l == 0) {
                float* ow = out_w + (size_t)t * TK;
                float* oi = out_i + (size_t)t * TK;
#pragma unroll
                for (int r = 0; r < 8; r++) ow[r] = wv[r] * scale;
#pragma unroll
                for (int r = 0; r < 8; r++) oi[r] = wi[r];
            }
        }
        __syncthreads();
    }
}

extern "C" void kernel_launch(void* const* d_in, const int* in_sizes, int n_in,
                              void* d_out, int out_size, void* d_ws, size_t ws_size,
                              hipStream_t stream) {
    const float* x = (const float*)d_in[0];
    const float* W = (const float*)d_in[1];
    const float* bias = (const float*)d_in[2];
    float* out = (float*)d_out;

    char* ws = (char*)d_ws;
    float* scores = (float*)ws;                                    // 8 MB
    _Float16* Wh = (_Float16*)(ws + (size_t)TOKENS * NEXP * 4);    // 2 MB
    _Float16* Wl = Wh + (size_t)NEXP * DIM;                        // 2 MB
    int* flag_cnt = (int*)(ws + (size_t)TOKENS * NEXP * 4 + (size_t)NEXP * DIM * 4);
    int* flag_list = flag_cnt + 4;                                 // up to 8192 ints

    wsplit<<<NEXP * DIM / 4 / 256, 256, 0, stream>>>(W, Wh, Wl, flag_cnt);

    dim3 gGemm(TOKENS / BM, NEXP / BN);   // 128 x 4 = 512 blocks, 2/CU
    score_gemm<<<gGemm, 256, 0, stream>>>(x, Wh, Wl, scores);

    route_kernel<<<TOKENS / 4, 256, 0, stream>>>(scores, bias, out,
                                                 out + (size_t)TOKENS * TK,
                                                 flag_cnt, flag_list);
    fixup_kernel<<<256, 256, 0, stream>>>(x, W, bias, flag_cnt, flag_list,
                                          out, out + (size_t)TOKENS * TK);
}

// Round 6
// 363.604 us; speedup vs baseline: 1.2411x; 1.2411x over previous
//
#include <hip/hip_runtime.h>
#include <math.h>

#define TOKENS 8192
#define DIM 4096
#define NEXP 256
#define TK 8
#define ROUTE_SCALE 2.5f
#define TH1 1e-5f   // score-gap trust threshold (~20x worst-case f16-split score error)
#define TH2 2e-5f   // group-score (sum of 2) gap threshold

#define PITCH 40    // halves per LDS row: 80 B = 5*16 -> b128-aligned every row, odd stride banks

typedef _Float16 half8 __attribute__((ext_vector_type(8)));
typedef float f4 __attribute__((ext_vector_type(4)));
union H8 { half8 v; int4 q; };

// ---------------------------------------------------------------------------
// Pre-kernel: pack W*256 into MFMA B-fragment order, f16 hi + residual*2048 lo.
// Frag (et,kc): lane holds B[k=kc*32+(lane>>4)*8+j][e=et*16+(lane&15)], j=0..7.
// Packed addr: ((et*128 + kc)*64 + lane)*8.  Also zeroes flag_cnt.
// ---------------------------------------------------------------------------
__global__ __launch_bounds__(256) void wsplit(const float* __restrict__ W,
                                              _Float16* __restrict__ Whp,
                                              _Float16* __restrict__ Wlp,
                                              int* __restrict__ flag_cnt) {
    int fi = blockIdx.x * 256 + threadIdx.x;        // 0 .. 16*128*64-1
    if (fi == 0) *flag_cnt = 0;
    int lane = fi & 63;
    int kc = (fi >> 6) & 127;
    int et = fi >> 13;
    int e = et * 16 + (lane & 15);
    int k = kc * 32 + ((lane >> 4) << 3);
    const float* src = W + (size_t)e * DIM + k;
    float4 a = *(const float4*)src;
    float4 b = *(const float4*)(src + 4);
    float f[8] = {a.x, a.y, a.z, a.w, b.x, b.y, b.z, b.w};
    H8 hh, hl;
#pragma unroll
    for (int j = 0; j < 8; j++) {
        float ws = f[j] * 256.0f;                   // exact (pow2)
        _Float16 h = (_Float16)ws;                  // RNE
        float r = ws - (float)h;                    // exact residual
        hh.v[j] = h;
        hl.v[j] = (_Float16)(r * 2048.0f);
    }
    *(int4*)(Whp + (size_t)fi * 8) = hh.q;
    *(int4*)(Wlp + (size_t)fi * 8) = hl.q;
}

// ---------------------------------------------------------------------------
// Kernel 1: partial logits = x @ W^T (k-chunked), 3-term f16-split MFMA.
// Block: 256 thr = 4 waves; tile m=64 (shared), n=128 (wave n=32, 2 et each).
// Grid (128 m, 2 n, 3 k-chunks) = 768 blocks = 3/CU, 12 waves/CU.
// A: f32 coalesced -> regs -> convert once -> padded LDS (dbuf). B: packed
// frags, coalesced dwordx4, reg double-buffered. Barrier = lgkmcnt-only
// s_barrier: global prefetches survive the barrier (no vmcnt(0) drain).
// ---------------------------------------------------------------------------
__global__ __launch_bounds__(256, 3) void score_gemm(const float* __restrict__ x,
                                                     const _Float16* __restrict__ Whp,
                                                     const _Float16* __restrict__ Wlp,
                                                     float* __restrict__ parts) {
    __shared__ __align__(16) _Float16 sAh[2][64 * PITCH];
    __shared__ __align__(16) _Float16 sAl[2][64 * PITCH];

    const int m0 = blockIdx.x * 64;
    const int nb = blockIdx.y;
    const int chunk = blockIdx.z;
    const int kcb = 43 * chunk;
    const int kce = kcb + (chunk == 2 ? 42 : 43);

    const int tid = threadIdx.x;
    const int lane = tid & 63;
    const int wave = tid >> 6;
    const int et0 = nb * 8 + wave * 2;              // two 16-expert tiles per wave

    // A staging: thread owns row srow, 8 consecutive k-floats at scol
    const int srow = tid >> 2;
    const int scol = (tid & 3) * 8;
    const int sidx = srow * PITCH + scol;
    const float* xrow = x + (size_t)(m0 + srow) * DIM + scol;

    f4 accH[4][2], accC[4][2];
#pragma unroll
    for (int i = 0; i < 4; i++)
#pragma unroll
        for (int j = 0; j < 2; j++) { accH[i][j] = (f4)0.0f; accC[i][j] = (f4)0.0f; }

    float4 ra[2][2];
    half8 bh[2][2], bl[2][2];

#define LOADRAW(S, KC)                                                         \
    {                                                                          \
        const float* p_ = xrow + (size_t)(KC) * 32;                            \
        ra[S][0] = *(const float4*)p_;                                         \
        ra[S][1] = *(const float4*)(p_ + 4);                                   \
    }

#define CONV(S, B_)                                                            \
    {                                                                          \
        float f_[8] = {ra[S][0].x, ra[S][0].y, ra[S][0].z, ra[S][0].w,         \
                       ra[S][1].x, ra[S][1].y, ra[S][1].z, ra[S][1].w};        \
        H8 hh_, hl_;                                                           \
        _Pragma("unroll") for (int j_ = 0; j_ < 8; j_++) {                     \
            float xv_ = f_[j_] * 16.0f;                                        \
            _Float16 hv_ = (_Float16)xv_;                                      \
            float r_ = xv_ - (float)hv_;                                       \
            hh_.v[j_] = hv_;                                                   \
            hl_.v[j_] = (_Float16)(r_ * 2048.0f);                              \
        }                                                                      \
        *(int4*)&sAh[B_][sidx] = hh_.q;                                        \
        *(int4*)&sAl[B_][sidx] = hl_.q;                                        \
    }

#define BLOAD(P_, KC)                                                          \
    _Pragma("unroll") for (int nt_ = 0; nt_ < 2; nt_++) {                      \
        size_t o_ = ((size_t)((et0 + nt_) * 128 + (KC)) * 64 + lane) * 8;      \
        bh[P_][nt_] = *(const half8*)(Whp + o_);                               \
        bl[P_][nt_] = *(const half8*)(Wlp + o_);                               \
    }

#define MFMA_PHASE(P)                                                          \
    _Pragma("unroll") for (int mt_ = 0; mt_ < 4; mt_++) {                      \
        int ra_ = (mt_ * 16 + (lane & 15)) * PITCH + ((lane >> 4) << 3);       \
        half8 ah_ = *(const half8*)&sAh[P][ra_];                               \
        half8 al_ = *(const half8*)&sAl[P][ra_];                               \
        _Pragma("unroll") for (int nt_ = 0; nt_ < 2; nt_++) {                  \
            accH[mt_][nt_] = __builtin_amdgcn_mfma_f32_16x16x32_f16(           \
                ah_, bh[P][nt_], accH[mt_][nt_], 0, 0, 0);                     \
            accC[mt_][nt_] = __builtin_amdgcn_mfma_f32_16x16x32_f16(           \
                ah_, bl[P][nt_], accC[mt_][nt_], 0, 0, 0);                     \
            accC[mt_][nt_] = __builtin_amdgcn_mfma_f32_16x16x32_f16(           \
                al_, bh[P][nt_], accC[mt_][nt_], 0, 0, 0);                     \
        }                                                                      \
    }

// LDS-writes-only barrier: does NOT drain vmcnt, so global prefetches stay in
// flight across it (the m97 vmcnt(0)-drain was the 75% stall in rounds 4/5).
#define BARRIER() asm volatile("s_waitcnt lgkmcnt(0)\n\ts_barrier" ::: "memory")

#define ITER(KC, P)                                                            \
    {                                                                          \
        if ((KC) + 1 < kce) { BLOAD(P ^ 1, (KC) + 1) }                         \
        if ((KC) + 2 < kce) { LOADRAW(P, (KC) + 2) }                           \
        MFMA_PHASE(P)                                                          \
        if ((KC) + 1 < kce) { CONV(P ^ 1, P ^ 1) }                             \
        BARRIER();                                                             \
    }

    // prologue: A(kcb)->buf0; raw A(kcb+1) staged; B(kcb) in regs parity 0
    LOADRAW(0, kcb)
    CONV(0, 0)
    LOADRAW(1, kcb + 1)
    BLOAD(0, kcb)
    BARRIER();

    int kc = kcb;
    while (kc + 2 <= kce) {
        ITER(kc, 0)
        ITER(kc + 1, 1)
        kc += 2;
    }
    if (kc < kce) { ITER(kc, 0) }

    // epilogue: partial = accH + accC/2048 (final /4096 applied in route).
    // C layout: col=lane&15, row=(lane>>4)*4+r.
    float* pc = parts + (size_t)chunk * TOKENS * NEXP;
#pragma unroll
    for (int mt = 0; mt < 4; mt++)
#pragma unroll
        for (int nt = 0; nt < 2; nt++) {
            int m = m0 + mt * 16 + ((lane >> 4) << 2);
            int e = (et0 + nt) * 16 + (lane & 15);
#pragma unroll
            for (int r = 0; r < 4; r++)
                pc[(size_t)(m + r) * NEXP + e] =
                    accH[mt][nt][r] + accC[mt][nt][r] * (1.0f / 2048.0f);
        }
#undef LOADRAW
#undef CONV
#undef BLOAD
#undef MFMA_PHASE
#undef BARRIER
#undef ITER
}

// ---------------------------------------------------------------------------
// Kernel 2: sum partials -> logits -> sigmoid -> routing + constant-threshold
// margin flagging. 4 tokens / 256-thr block, 1 wave per token.
// ---------------------------------------------------------------------------
__global__ __launch_bounds__(256) void route_kernel(const float* __restrict__ parts,
                                                    const float* __restrict__ bias,
                                                    float* __restrict__ out_w,
                                                    float* __restrict__ out_i,
                                                    int* __restrict__ flag_cnt,
                                                    int* __restrict__ flag_list) {
    const int t = blockIdx.x * 4 + (threadIdx.x >> 6);
    const int l = threadIdx.x & 63;

    const float* p = parts + (size_t)t * NEXP + (l << 2);
    float4 q0 = *(const float4*)p;
    float4 q1 = *(const float4*)(p + (size_t)TOKENS * NEXP);
    float4 q2 = *(const float4*)(p + (size_t)2 * TOKENS * NEXP);
    float4 b4 = *(const float4*)&bias[l << 2];
    float sc[4], sb[4];
    {
        float lg0 = (q0.x + q1.x + q2.x) * (1.0f / 4096.0f);
        float lg1 = (q0.y + q1.y + q2.y) * (1.0f / 4096.0f);
        float lg2 = (q0.z + q1.z + q2.z) * (1.0f / 4096.0f);
        float lg3 = (q0.w + q1.w + q2.w) * (1.0f / 4096.0f);
        sc[0] = 1.0f / (1.0f + expf(-lg0));
        sc[1] = 1.0f / (1.0f + expf(-lg1));
        sc[2] = 1.0f / (1.0f + expf(-lg2));
        sc[3] = 1.0f / (1.0f + expf(-lg3));
        sb[0] = sc[0] + b4.x; sb[1] = sc[1] + b4.y;
        sb[2] = sc[2] + b4.z; sb[3] = sc[3] + b4.w;
    }

    // per-lane top-3 of its 4 biased scores
    float v1 = sb[0], v2 = -1e30f, v3 = -1e30f;
#pragma unroll
    for (int c = 1; c < 4; c++) {
        float xv = sb[c];
        if (xv > v1) { v3 = v2; v2 = v1; v1 = xv; }
        else if (xv > v2) { v3 = v2; v2 = xv; }
        else if (xv > v3) { v3 = xv; }
    }

    // butterfly top-3 merge across the 8 lanes of the group
#pragma unroll
    for (int m = 1; m < 8; m <<= 1) {
        float o1 = __shfl_xor(v1, m, 64);
        float o2 = __shfl_xor(v2, m, 64);
        float o3 = __shfl_xor(v3, m, 64);
        bool aw = (v1 >= o1);
        float A1 = aw ? v1 : o1, A2 = aw ? v2 : o2, A3 = aw ? v3 : o3;
        float B1 = aw ? o1 : v1, B2 = aw ? o2 : v2;
        float n2, n3;
        if (A2 >= B1) { n2 = A2; n3 = fmaxf(B1, A3); }
        else          { n2 = B1; n3 = fmaxf(A2, B2); }
        v1 = A1; v2 = n2; v3 = n3;
    }
    float gscore = v1 + v2;
    float gap23 = v2 - v3;                  // within-group top2-vs-3 gap
#pragma unroll
    for (int m = 8; m < 64; m <<= 1) gap23 = fminf(gap23, __shfl_xor(gap23, m, 64));

    float gs[8];
#pragma unroll
    for (int g = 0; g < 8; g++) gs[g] = __shfl(gscore, g << 3, 64);

    const int mygrp = l >> 3;
    int rank = 0;
#pragma unroll
    for (int g = 0; g < 8; g++) {
        bool better = (gs[g] > gscore) || (gs[g] == gscore && g < mygrp);
        rank += (g != mygrp && better) ? 1 : 0;
    }
    const bool sel = rank < 4;

    // group 4th-vs-5th gap
    float minsel = 1e30f, maxuns = -1e30f;
#pragma unroll
    for (int g = 0; g < 8; g++) {
        int rg = 0;
#pragma unroll
        for (int g2 = 0; g2 < 8; g2++)
            rg += (g2 != g && ((gs[g2] > gs[g]) || (gs[g2] == gs[g] && g2 < g))) ? 1 : 0;
        if (rg < 4) minsel = fminf(minsel, gs[g]); else maxuns = fmaxf(maxuns, gs[g]);
    }
    float gap45 = minsel - maxuns;

    float cand[4];
#pragma unroll
    for (int c = 0; c < 4; c++) cand[c] = sel ? sb[c] : 0.0f;

    // serial top-9 extraction (9th only for the boundary gap)
    float wv[8], wi[8], vb[9];
    float wsum = 0.0f;
#pragma unroll
    for (int r = 0; r < 9; r++) {
        float v = cand[0];
        int idx = (l << 2);
#pragma unroll
        for (int c = 1; c < 4; c++) {
            if (cand[c] > v) { v = cand[c]; idx = (l << 2) + c; }
        }
#pragma unroll
        for (int m = 32; m >= 1; m >>= 1) {
            float ov = __shfl_xor(v, m, 64);
            int oi = __shfl_xor(idx, m, 64);
            if (ov > v || (ov == v && oi < idx)) { v = ov; idx = oi; }
        }
        vb[r] = v;
        if (r < 8) {
            const int cc = idx & 3;
            const bool own = (idx >> 2) == l;
            cand[0] = (own && cc == 0) ? -__builtin_inff() : cand[0];
            cand[1] = (own && cc == 1) ? -__builtin_inff() : cand[1];
            cand[2] = (own && cc == 2) ? -__builtin_inff() : cand[2];
            cand[3] = (own && cc == 3) ? -__builtin_inff() : cand[3];
            float tmp = (cc == 0) ? sc[0] : (cc == 1) ? sc[1] : (cc == 2) ? sc[2] : sc[3];
            float ws = __shfl(tmp, idx >> 2, 64);
            wv[r] = ws;
            wi[r] = (float)idx;
            wsum += ws;
        }
    }
    float mingap = 1e30f;
#pragma unroll
    for (int r = 0; r < 8; r++) mingap = fminf(mingap, vb[r] - vb[r + 1]);

    const float scale = ROUTE_SCALE / wsum;
    if (l == 0) {
        float* ow = out_w + (size_t)t * TK;
        float* oi = out_i + (size_t)t * TK;
#pragma unroll
        for (int r = 0; r < 8; r++) ow[r] = wv[r] * scale;
#pragma unroll
        for (int r = 0; r < 8; r++) oi[r] = wi[r];
        if (gap23 < TH1 || gap45 < TH2 || mingap < TH1) {
            int pos = atomicAdd(flag_cnt, 1);
            flag_list[pos] = t;
        }
    }
}

// ---------------------------------------------------------------------------
// Kernel 3: fixup — flagged tokens recomputed with the bit-identical serial
// fp32 fmaf chain (== round-1 passing kernel) + exact re-route.
// ---------------------------------------------------------------------------
__global__ __launch_bounds__(256) void fixup_kernel(const float* __restrict__ x,
                                                    const float* __restrict__ W,
                                                    const float* __restrict__ bias,
                                                    const int* __restrict__ flag_cnt,
                                                    const int* __restrict__ flag_list,
                                                    float* __restrict__ out_w,
                                                    float* __restrict__ out_i) {
    __shared__ float S[NEXP];
    const int n = *flag_cnt;
    for (int i = blockIdx.x; i < n; i += gridDim.x) {
        const int t = flag_list[i];
        const float* xr = x + (size_t)t * DIM;
        const float* wr = W + (size_t)threadIdx.x * DIM;
        float acc = 0.0f;
        for (int k = 0; k < DIM; k += 4) {           // strictly k-serial fmaf chain
            float4 xv = *(const float4*)(xr + k);
            float4 wv = *(const float4*)(wr + k);
            acc = fmaf(xv.x, wv.x, acc);
            acc = fmaf(xv.y, wv.y, acc);
            acc = fmaf(xv.z, wv.z, acc);
            acc = fmaf(xv.w, wv.w, acc);
        }
        S[threadIdx.x] = 1.0f / (1.0f + expf(-acc));
        __syncthreads();
        if (threadIdx.x < 64) {
            const int l = threadIdx.x;
            float sc[4] = {S[4 * l], S[4 * l + 1], S[4 * l + 2], S[4 * l + 3]};
            float4 b4 = *(const float4*)&bias[4 * l];
            float sb[4] = {sc[0] + b4.x, sc[1] + b4.y, sc[2] + b4.z, sc[3] + b4.w};

            float h1 = fmaxf(sb[0], sb[1]), q1 = fminf(sb[0], sb[1]);
            float h2 = fmaxf(sb[2], sb[3]), q2 = fminf(sb[2], sb[3]);
            float m1 = fmaxf(h1, h2);
            float m2 = fmaxf(fminf(h1, h2), fmaxf(q1, q2));
#pragma unroll
            for (int m = 1; m < 8; m <<= 1) {
                float o1 = __shfl_xor(m1, m, 64);
                float o2 = __shfl_xor(m2, m, 64);
                float nm1 = fmaxf(m1, o1);
                float nm2 = fmaxf(fminf(m1, o1), fmaxf(m2, o2));
                m1 = nm1; m2 = nm2;
            }
            float gscore = m1 + m2;
            float gs[8];
#pragma unroll
            for (int g = 0; g < 8; g++) gs[g] = __shfl(gscore, g << 3, 64);
            const int mygrp = l >> 3;
            int rank = 0;
#pragma unroll
            for (int g = 0; g < 8; g++) {
                bool better = (gs[g] > gscore) || (gs[g] == gscore && g < mygrp);
                rank += (g != mygrp && better) ? 1 : 0;
            }
            const bool selg = rank < 4;
            float cand[4];
#pragma unroll
            for (int c = 0; c < 4; c++) cand[c] = selg ? sb[c] : 0.0f;
            float wv[8], wi[8];
            float wsum = 0.0f;
#pragma unroll
            for (int r = 0; r < 8; r++) {
                float v = cand[0];
                int idx = (l << 2);
#pragma unroll
                for (int c = 1; c < 4; c++) {
                    if (cand[c] > v) { v = cand[c]; idx = (l << 2) + c; }
                }
#pragma unroll
                for (int m = 32; m >= 1; m >>= 1) {
                    float ov = __shfl_xor(v, m, 64);
                    int oi = __shfl_xor(idx, m, 64);
                    if (ov > v || (ov == v && oi < idx)) { v = ov; idx = oi; }
                }
                const int cc = idx & 3;
                const bool own = (idx >> 2) == l;
                cand[0] = (own && cc == 0) ? -__builtin_inff() : cand[0];
                cand[1] = (own && cc == 1) ? -__builtin_inff() : cand[1];
                cand[2] = (own && cc == 2) ? -__builtin_inff() : cand[2];
                cand[3] = (own && cc == 3) ? -__builtin_inff() : cand[3];
                float tmp = (cc == 0) ? sc[0] : (cc == 1) ? sc[1] : (cc == 2) ? sc[2] : sc[3];
                float ws = __shfl(tmp, idx >> 2, 64);
                wv[r] = ws;
                wi[r] = (float)idx;
                wsum += ws;
            }
            const float scale = ROUTE_SCALE / wsum;
            if (l == 0) {
                float* ow = out_w + (size_t)t * TK;
                float* oi = out_i + (size_t)t * TK;
#pragma unroll
                for (int r = 0; r < 8; r++) ow[r] = wv[r] * scale;
#pragma unroll
                for (int r = 0; r < 8; r++) oi[r] = wi[r];
            }
        }
        __syncthreads();
    }
}

extern "C" void kernel_launch(void* const* d_in, const int* in_sizes, int n_in,
                              void* d_out, int out_size, void* d_ws, size_t ws_size,
                              hipStream_t stream) {
    const float* x = (const float*)d_in[0];
    const float* W = (const float*)d_in[1];
    const float* bias = (const float*)d_in[2];
    float* out = (float*)d_out;

    char* ws = (char*)d_ws;
    float* parts = (float*)ws;                                        // 3 x 8 MB
    _Float16* Whp = (_Float16*)(ws + (size_t)3 * TOKENS * NEXP * 4);  // 2 MB
    _Float16* Wlp = Whp + (size_t)NEXP * DIM;                         // 2 MB
    int* flag_cnt = (int*)((char*)(Wlp + (size_t)NEXP * DIM));
    int* flag_list = flag_cnt + 4;                                    // up to 8192 ints

    wsplit<<<512, 256, 0, stream>>>(W, Whp, Wlp, flag_cnt);

    dim3 gGemm(TOKENS / 64, 2, 3);   // 768 blocks = 3/CU
    score_gemm<<<gGemm, 256, 0, stream>>>(x, Whp, Wlp, parts);

    route_kernel<<<TOKENS / 4, 256, 0, stream>>>(parts, bias, out,
                                                 out + (size_t)TOKENS * TK,
                                                 flag_cnt, flag_list);
    fixup_kernel<<<1024, 256, 0, stream>>>(x, W, bias, flag_cnt, flag_list,
                                           out, out + (size_t)TOKENS * TK);
}